// Round 1
// baseline (885.139 us; speedup 1.0000x reference)
//
#include <hip/hip_runtime.h>

#define NN 100000
#define NE 3200000
#define D  128
#define NB ((NN + 255) / 256)   // 391 scan blocks

typedef __attribute__((ext_vector_type(8))) short bf16x8;
typedef __attribute__((ext_vector_type(4))) float f32x4;

__device__ __forceinline__ float bf2f(unsigned int u) {      // u = bf16 bits
    union { unsigned int i; float f; } v; v.i = u << 16; return v.f;
}
__device__ __forceinline__ float bits2f(unsigned int u) {    // raw f32 bits
    union { unsigned int i; float f; } v; v.i = u; return v.f;
}
__device__ __forceinline__ unsigned int f2bf(float f) {      // RNE bf16
    union { float f; unsigned int i; } v; v.f = f;
    unsigned int u = v.i;
    return (u + 0x7fffu + ((u >> 16) & 1u)) >> 16;
}
__device__ __forceinline__ unsigned int f2w15(float f) {     // 15-bit: sign0,8exp,6man RNE
    union { float f; unsigned int i; } v; v.f = f;
    unsigned int u = v.i;
    return (u + 0xFFFFu + ((u >> 17) & 1u)) >> 17;           // f in [0,1] -> no overflow
}

// --- 0. detect edge_index element width: int64 -> odd int32 slots (high words) all zero ---
__global__ void detect_kernel(const int* __restrict__ ei, int* __restrict__ flag) {
    int t = threadIdx.x;
    int v = ei[2 * t + 1];
    unsigned long long ball = __ballot(v != 0);
    if (t == 0) flag[0] = (ball == 0ull) ? 1 : 0;   // 1 => int64
}

// --- 1. h = bf16(x @ W), SLICE-MAJOR layout: hb[slice][node][16]  (slice = 16 feats, 3.2 MB) ---
__global__ __launch_bounds__(256) void mgemm_kernel(const float* __restrict__ x,
        const float* __restrict__ W, unsigned short* __restrict__ hb) {
    __shared__ unsigned short WT[16 * 128 * 8];    // 32 KB
    int t = threadIdx.x;
    {
        int n = t & 127, half = t >> 7;
        for (int it = 0; it < 8; ++it) {
            int kb = half * 8 + it;                // k-chunk 0..15
            union { unsigned short s[8]; uint4 v; } pk;
#pragma unroll
            for (int j = 0; j < 8; ++j)
                pk.s[j] = (unsigned short)f2bf(W[(kb * 8 + j) * D + n]);
            *(uint4*)&WT[(kb * 128 + n) * 8] = pk.v;
        }
    }
    __syncthreads();
    int l = t & 63, w = t >> 6;
    int q = l >> 4, m = l & 15;
    long mbase = (long)blockIdx.x * 128 + w * 32;
    long r0 = mbase + m;      if (r0 > NN - 1) r0 = NN - 1;   // clamp: no OOB reads
    long r1 = mbase + 16 + m; if (r1 > NN - 1) r1 = NN - 1;
    const float* a0p = x + r0 * D + q * 8;
    const float* a1p = x + r1 * D + q * 8;
    f32x4 acc[2][8];
#pragma unroll
    for (int mt = 0; mt < 2; ++mt)
#pragma unroll
        for (int nt = 0; nt < 8; ++nt) acc[mt][nt] = (f32x4){0.f, 0.f, 0.f, 0.f};
#pragma unroll
    for (int kc = 0; kc < 4; ++kc) {
        float4 va0 = *(const float4*)(a0p + kc * 32);
        float4 va1 = *(const float4*)(a0p + kc * 32 + 4);
        float4 vb0 = *(const float4*)(a1p + kc * 32);
        float4 vb1 = *(const float4*)(a1p + kc * 32 + 4);
        union { unsigned short s[8]; bf16x8 v; } ua, ub;
        ua.s[0] = (unsigned short)f2bf(va0.x); ua.s[1] = (unsigned short)f2bf(va0.y);
        ua.s[2] = (unsigned short)f2bf(va0.z); ua.s[3] = (unsigned short)f2bf(va0.w);
        ua.s[4] = (unsigned short)f2bf(va1.x); ua.s[5] = (unsigned short)f2bf(va1.y);
        ua.s[6] = (unsigned short)f2bf(va1.z); ua.s[7] = (unsigned short)f2bf(va1.w);
        ub.s[0] = (unsigned short)f2bf(vb0.x); ub.s[1] = (unsigned short)f2bf(vb0.y);
        ub.s[2] = (unsigned short)f2bf(vb0.z); ub.s[3] = (unsigned short)f2bf(vb0.w);
        ub.s[4] = (unsigned short)f2bf(vb1.x); ub.s[5] = (unsigned short)f2bf(vb1.y);
        ub.s[6] = (unsigned short)f2bf(vb1.z); ub.s[7] = (unsigned short)f2bf(vb1.w);
        const bf16x8* bp = (const bf16x8*)WT + (kc * 4 + q) * 128 + m;
#pragma unroll
        for (int nt = 0; nt < 8; ++nt) {
            bf16x8 bfr = bp[nt * 16];
            acc[0][nt] = __builtin_amdgcn_mfma_f32_16x16x32_bf16(ua.v, bfr, acc[0][nt], 0, 0, 0);
            acc[1][nt] = __builtin_amdgcn_mfma_f32_16x16x32_bf16(ub.v, bfr, acc[1][nt], 0, 0, 0);
        }
    }
#pragma unroll
    for (int mt = 0; mt < 2; ++mt) {
        long rowbase = mbase + mt * 16;
#pragma unroll
        for (int nt = 0; nt < 8; ++nt)
#pragma unroll
            for (int r = 0; r < 4; ++r) {
                long row = rowbase + q * 4 + r;      // C/D: col=lane&15, row=quad*4+reg
                if (row < NN)                        // slice-major: hb[nt][row][m]
                    hb[((size_t)nt * NN + row) * 16 + m] = (unsigned short)f2bf(acc[mt][nt][r]);
            }
    }
}

// --- 2. count + weighted-degree per dst; atomic RETURN = within-bucket rank (u8) ---
__global__ void hist_kernel(const int* __restrict__ ei, const float* __restrict__ ew,
                            int* __restrict__ cnt, float* __restrict__ deg,
                            unsigned char* __restrict__ rnk, const int* __restrict__ flag) {
    int s = flag[0];
    int e = blockIdx.x * 256 + threadIdx.x;
    if (e < NE) {
        int d = s ? ((const int2*)ei)[NE + e].x : ei[NE + e];
        int r = atomicAdd(&cnt[d], 1);
        rnk[e] = (unsigned char)r;
        atomicAdd(&deg[d], ew[e]);
    }
}

// --- 3a/3b/3c. three-phase exclusive scan -> row_ptr ; scan3 also emits dis = rsqrt(1+deg) ---
__global__ __launch_bounds__(256) void scan1_kernel(const int* __restrict__ cnt,
                                                    int* __restrict__ part) {
    __shared__ int red[256];
    int t = threadIdx.x, i = blockIdx.x * 256 + t;
    red[t] = (i < NN) ? cnt[i] : 0;
    __syncthreads();
    for (int off = 128; off; off >>= 1) {
        if (t < off) red[t] += red[t + off];
        __syncthreads();
    }
    if (t == 0) part[blockIdx.x] = red[0];
}
__global__ __launch_bounds__(512) void scan2_kernel(int* __restrict__ part) {
    __shared__ int s[512];
    int t = threadIdx.x;
    s[t] = (t < NB) ? part[t] : 0;
    __syncthreads();
    for (int off = 1; off < 512; off <<= 1) {
        int v = (t >= off) ? s[t - off] : 0;
        __syncthreads();
        s[t] += v;
        __syncthreads();
    }
    if (t < NB) part[t] = (t > 0) ? s[t - 1] : 0;
}
__global__ __launch_bounds__(256) void scan3_kernel(const int* __restrict__ cnt,
        const int* __restrict__ part, const float* __restrict__ deg,
        int* __restrict__ row_ptr, float* __restrict__ dis) {
    __shared__ int s[256];
    int t = threadIdx.x, i = blockIdx.x * 256 + t;
    int v = (i < NN) ? cnt[i] : 0;
    s[t] = v;
    __syncthreads();
    for (int off = 1; off < 256; off <<= 1) {
        int u = (t >= off) ? s[t - off] : 0;
        __syncthreads();
        s[t] += u;
        __syncthreads();
    }
    int base = part[blockIdx.x];
    if (i < NN) {
        row_ptr[i] = base + s[t] - v;
        dis[i] = rsqrtf(1.0f + deg[i]);          // self-loop weight 1 included
    }
    if (i == NN - 1) row_ptr[NN] = base + s[t];
}

// --- 4. bucket fill, atomic-free; csr word = src<<15 | f2w15(dis[src]*w*dis[dst]) ---
__global__ void fill_kernel(const int* __restrict__ ei, const float* __restrict__ ew,
                            const unsigned char* __restrict__ rnk, const int* __restrict__ row_ptr,
                            const float* __restrict__ dis, unsigned int* __restrict__ csr,
                            const int* __restrict__ flag) {
    int s = flag[0];
    int e = blockIdx.x * 256 + threadIdx.x;
    if (e < NE) {
        int src, dst;
        if (s) { src = ((const int2*)ei)[e].x; dst = ((const int2*)ei)[NE + e].x; }
        else   { src = ei[e];                  dst = ei[NE + e]; }
        int pos = row_ptr[dst] + rnk[e];
        float nw = dis[src] * ew[e] * dis[dst];          // in (0,1]
        csr[pos] = ((unsigned int)src << 15) | f2w15(nw);
    }
}

// --- 5. pull, feature-sliced: slice s (16 feats, 3.2 MB) pinned to XCD s via blockIdx&7.
//        4 lanes/node/slice, each lane owns 4 feats (1 uint2 of hb). nw pre-baked in csr. ---
__global__ __launch_bounds__(256) void pull_kernel(const uint2* __restrict__ hb2,
        const float* __restrict__ dis, const int* __restrict__ row_ptr,
        const unsigned int* __restrict__ csr, const float4* __restrict__ bias4,
        float* __restrict__ out) {
    int slice = blockIdx.x & 7;                   // measured round-robin blockIdx -> XCD
    int n = (blockIdx.x >> 3) * 64 + (threadIdx.x >> 2);
    int fl = threadIdx.x & 3;                     // uint2 (4 feats) within slice
    if (n >= NN) return;
    const uint2* hs = hb2 + (size_t)slice * (NN * 4);
    float dn = dis[n], ss = dn * dn;
    uint2 a = hs[n * 4 + fl];                     // self-loop term
    float a0 = bits2f(a.x << 16) * ss;
    float a1 = bits2f(a.x & 0xffff0000u) * ss;
    float a2 = bits2f(a.y << 16) * ss;
    float a3 = bits2f(a.y & 0xffff0000u) * ss;
    int e = row_ptr[n], end = row_ptr[n + 1];
    for (; e + 3 < end; e += 4) {                 // MLP=4 independent gathers
        unsigned int c0 = __builtin_nontemporal_load(csr + e);
        unsigned int c1 = __builtin_nontemporal_load(csr + e + 1);
        unsigned int c2 = __builtin_nontemporal_load(csr + e + 2);
        unsigned int c3 = __builtin_nontemporal_load(csr + e + 3);
        uint2 u0 = hs[(c0 >> 15) * 4 + fl];
        uint2 u1 = hs[(c1 >> 15) * 4 + fl];
        uint2 u2 = hs[(c2 >> 15) * 4 + fl];
        uint2 u3 = hs[(c3 >> 15) * 4 + fl];
        float w0 = bits2f(c0 << 17), w1 = bits2f(c1 << 17);
        float w2 = bits2f(c2 << 17), w3 = bits2f(c3 << 17);
        a0 += bits2f(u0.x << 16) * w0; a1 += bits2f(u0.x & 0xffff0000u) * w0;
        a2 += bits2f(u0.y << 16) * w0; a3 += bits2f(u0.y & 0xffff0000u) * w0;
        a0 += bits2f(u1.x << 16) * w1; a1 += bits2f(u1.x & 0xffff0000u) * w1;
        a2 += bits2f(u1.y << 16) * w1; a3 += bits2f(u1.y & 0xffff0000u) * w1;
        a0 += bits2f(u2.x << 16) * w2; a1 += bits2f(u2.x & 0xffff0000u) * w2;
        a2 += bits2f(u2.y << 16) * w2; a3 += bits2f(u2.y & 0xffff0000u) * w2;
        a0 += bits2f(u3.x << 16) * w3; a1 += bits2f(u3.x & 0xffff0000u) * w3;
        a2 += bits2f(u3.y << 16) * w3; a3 += bits2f(u3.y & 0xffff0000u) * w3;
    }
    for (; e < end; ++e) {
        unsigned int c = __builtin_nontemporal_load(csr + e);
        uint2 u = hs[(c >> 15) * 4 + fl];
        float w = bits2f(c << 17);
        a0 += bits2f(u.x << 16) * w; a1 += bits2f(u.x & 0xffff0000u) * w;
        a2 += bits2f(u.y << 16) * w; a3 += bits2f(u.y & 0xffff0000u) * w;
    }
    float4 bv = bias4[slice * 4 + fl];
    f32x4 r = {a0 + bv.x, a1 + bv.y, a2 + bv.z, a3 + bv.w};
    __builtin_nontemporal_store(r, (f32x4*)out + ((size_t)n * 32 + slice * 4 + fl));
}

extern "C" void kernel_launch(void* const* d_in, const int* in_sizes, int n_in,
                              void* d_out, int out_size, void* d_ws, size_t ws_size,
                              hipStream_t stream) {
    const float* x  = (const float*)d_in[0];
    const int*   ei = (const int*)d_in[1];
    const float* ew = (const float*)d_in[2];
    const float* W  = (const float*)d_in[3];
    const float* b  = (const float*)d_in[4];
    float* out = (float*)d_out;

    // workspace (~43.6 MB)
    float*          dis     = (float*)d_ws;                    // NN
    float*          deg     = dis + NN;                        // NN
    int*            cnt     = (int*)(deg + NN);                // NN
    int*            row_ptr = cnt + NN;                        // NN+1
    int*            part    = row_ptr + NN + 1;                // 512
    int*            flag    = part + 512;                      // 1
    unsigned char*  rnk     = (unsigned char*)(((uintptr_t)(flag + 1) + 15) & ~(uintptr_t)15); // NE u8
    unsigned int*   csr     = (unsigned int*)(rnk + NE);       // NE u32
    unsigned short* hb      = (unsigned short*)(csr + NE);     // NN*128 bf16, slice-major (25.6 MB)

    detect_kernel<<<1, 64, 0, stream>>>(ei, flag);
    hipMemsetAsync(deg, 0, 2 * NN * sizeof(float), stream);    // deg + cnt (contiguous)
    mgemm_kernel<<<(NN + 127) / 128, 256, 0, stream>>>(x, W, hb);
    hist_kernel<<<(NE + 255) / 256, 256, 0, stream>>>(ei, ew, cnt, deg, rnk, flag);
    scan1_kernel<<<NB, 256, 0, stream>>>(cnt, part);
    scan2_kernel<<<1, 512, 0, stream>>>(part);
    scan3_kernel<<<NB, 256, 0, stream>>>(cnt, part, deg, row_ptr, dis);
    fill_kernel<<<(NE + 255) / 256, 256, 0, stream>>>(ei, ew, rnk, row_ptr, dis, csr, flag);
    pull_kernel<<<8 * ((NN + 63) / 64), 256, 0, stream>>>((const uint2*)hb, dis, row_ptr, csr,
                                                          (const float4*)b, out);
}

// Round 3
// 767.285 us; speedup vs baseline: 1.1536x; 1.1536x over previous
//
#include <hip/hip_runtime.h>

#define NN 100000
#define NE 3200000
#define D  128
#define NB ((NN + 255) / 256)   // 391 scan blocks

typedef __attribute__((ext_vector_type(8))) short bf16x8;
typedef __attribute__((ext_vector_type(4))) float f32x4;
typedef __attribute__((ext_vector_type(2))) float f32x2;

__device__ __forceinline__ float bf2f(unsigned int u) {      // u = bf16 bits
    union { unsigned int i; float f; } v; v.i = u << 16; return v.f;
}
__device__ __forceinline__ float bits2f(unsigned int u) {    // raw f32 bits
    union { unsigned int i; float f; } v; v.i = u; return v.f;
}
__device__ __forceinline__ unsigned int f2bf(float f) {      // RNE bf16
    union { float f; unsigned int i; } v; v.f = f;
    unsigned int u = v.i;
    return (u + 0x7fffu + ((u >> 16) & 1u)) >> 16;
}

// --- 0. detect edge_index element width: int64 -> odd int32 slots (high words) all zero ---
__global__ void detect_kernel(const int* __restrict__ ei, int* __restrict__ flag) {
    int t = threadIdx.x;
    int v = ei[2 * t + 1];
    unsigned long long ball = __ballot(v != 0);
    if (t == 0) flag[0] = (ball == 0ull) ? 1 : 0;   // 1 => int64
}

// --- 1. h = bf16(x @ W), SLICE-MAJOR layout: hb[slice][node][16]  (slice = 16 feats, 3.2 MB) ---
__global__ __launch_bounds__(256) void mgemm_kernel(const float* __restrict__ x,
        const float* __restrict__ W, unsigned short* __restrict__ hb) {
    __shared__ unsigned short WT[16 * 128 * 8];    // 32 KB
    int t = threadIdx.x;
    {
        int n = t & 127, half = t >> 7;
        for (int it = 0; it < 8; ++it) {
            int kb = half * 8 + it;                // k-chunk 0..15
            union { unsigned short s[8]; uint4 v; } pk;
#pragma unroll
            for (int j = 0; j < 8; ++j)
                pk.s[j] = (unsigned short)f2bf(W[(kb * 8 + j) * D + n]);
            *(uint4*)&WT[(kb * 128 + n) * 8] = pk.v;
        }
    }
    __syncthreads();
    int l = t & 63, w = t >> 6;
    int q = l >> 4, m = l & 15;
    long mbase = (long)blockIdx.x * 128 + w * 32;
    long r0 = mbase + m;      if (r0 > NN - 1) r0 = NN - 1;   // clamp: no OOB reads
    long r1 = mbase + 16 + m; if (r1 > NN - 1) r1 = NN - 1;
    const float* a0p = x + r0 * D + q * 8;
    const float* a1p = x + r1 * D + q * 8;
    f32x4 acc[2][8];
#pragma unroll
    for (int mt = 0; mt < 2; ++mt)
#pragma unroll
        for (int nt = 0; nt < 8; ++nt) acc[mt][nt] = (f32x4){0.f, 0.f, 0.f, 0.f};
#pragma unroll
    for (int kc = 0; kc < 4; ++kc) {
        float4 va0 = *(const float4*)(a0p + kc * 32);
        float4 va1 = *(const float4*)(a0p + kc * 32 + 4);
        float4 vb0 = *(const float4*)(a1p + kc * 32);
        float4 vb1 = *(const float4*)(a1p + kc * 32 + 4);
        union { unsigned short s[8]; bf16x8 v; } ua, ub;
        ua.s[0] = (unsigned short)f2bf(va0.x); ua.s[1] = (unsigned short)f2bf(va0.y);
        ua.s[2] = (unsigned short)f2bf(va0.z); ua.s[3] = (unsigned short)f2bf(va0.w);
        ua.s[4] = (unsigned short)f2bf(va1.x); ua.s[5] = (unsigned short)f2bf(va1.y);
        ua.s[6] = (unsigned short)f2bf(va1.z); ua.s[7] = (unsigned short)f2bf(va1.w);
        ub.s[0] = (unsigned short)f2bf(vb0.x); ub.s[1] = (unsigned short)f2bf(vb0.y);
        ub.s[2] = (unsigned short)f2bf(vb0.z); ub.s[3] = (unsigned short)f2bf(vb0.w);
        ub.s[4] = (unsigned short)f2bf(vb1.x); ub.s[5] = (unsigned short)f2bf(vb1.y);
        ub.s[6] = (unsigned short)f2bf(vb1.z); ub.s[7] = (unsigned short)f2bf(vb1.w);
        const bf16x8* bp = (const bf16x8*)WT + (kc * 4 + q) * 128 + m;
#pragma unroll
        for (int nt = 0; nt < 8; ++nt) {
            bf16x8 bfr = bp[nt * 16];
            acc[0][nt] = __builtin_amdgcn_mfma_f32_16x16x32_bf16(ua.v, bfr, acc[0][nt], 0, 0, 0);
            acc[1][nt] = __builtin_amdgcn_mfma_f32_16x16x32_bf16(ub.v, bfr, acc[1][nt], 0, 0, 0);
        }
    }
#pragma unroll
    for (int mt = 0; mt < 2; ++mt) {
        long rowbase = mbase + mt * 16;
#pragma unroll
        for (int nt = 0; nt < 8; ++nt)
#pragma unroll
            for (int r = 0; r < 4; ++r) {
                long row = rowbase + q * 4 + r;      // C/D: col=lane&15, row=quad*4+reg
                if (row < NN)                        // slice-major: hb[nt][row][m]
                    hb[((size_t)nt * NN + row) * 16 + m] = (unsigned short)f2bf(acc[mt][nt][r]);
            }
    }
}

// --- 2. count per dst; atomic RETURN VALUE = within-bucket rank (u8: max in-deg ~70) ---
__global__ void hist_kernel(const int* __restrict__ ei, int* __restrict__ cnt,
                            unsigned char* __restrict__ rnk, const int* __restrict__ flag) {
    int s = flag[0];
    int e = blockIdx.x * 256 + threadIdx.x;
    if (e < NE) {
        int r = atomicAdd(&cnt[ei[(NE + e) << s]], 1);
        rnk[e] = (unsigned char)r;
    }
}

// --- 3a/3b/3c. three-phase exclusive scan -> row_ptr ---
__global__ __launch_bounds__(256) void scan1_kernel(const int* __restrict__ cnt,
                                                    int* __restrict__ part) {
    __shared__ int red[256];
    int t = threadIdx.x, i = blockIdx.x * 256 + t;
    red[t] = (i < NN) ? cnt[i] : 0;
    __syncthreads();
    for (int off = 128; off; off >>= 1) {
        if (t < off) red[t] += red[t + off];
        __syncthreads();
    }
    if (t == 0) part[blockIdx.x] = red[0];
}
__global__ __launch_bounds__(512) void scan2_kernel(int* __restrict__ part) {
    __shared__ int s[512];
    int t = threadIdx.x;
    s[t] = (t < NB) ? part[t] : 0;
    __syncthreads();
    for (int off = 1; off < 512; off <<= 1) {
        int v = (t >= off) ? s[t - off] : 0;
        __syncthreads();
        s[t] += v;
        __syncthreads();
    }
    if (t < NB) part[t] = (t > 0) ? s[t - 1] : 0;
}
__global__ __launch_bounds__(256) void scan3_kernel(const int* __restrict__ cnt,
        const int* __restrict__ part, int* __restrict__ row_ptr) {
    __shared__ int s[256];
    int t = threadIdx.x, i = blockIdx.x * 256 + t;
    int v = (i < NN) ? cnt[i] : 0;
    s[t] = v;
    __syncthreads();
    for (int off = 1; off < 256; off <<= 1) {
        int u = (t >= off) ? s[t - off] : 0;
        __syncthreads();
        s[t] += u;
        __syncthreads();
    }
    int base = part[blockIdx.x];
    if (i < NN) row_ptr[i] = base + s[t] - v;
    if (i == NN - 1) row_ptr[NN] = base + s[t];
}

// --- 4. bucket fill, atomic-free: pos = row_ptr[dst] + rnk[e] ---
__global__ void fill_kernel(const int* __restrict__ ei, const float* __restrict__ ew,
                            const unsigned char* __restrict__ rnk,
                            const int* __restrict__ row_ptr, unsigned int* __restrict__ csr,
                            const int* __restrict__ flag) {
    int s = flag[0];
    int e = blockIdx.x * 256 + threadIdx.x;
    if (e < NE) {
        int src = ei[e << s];
        int dst = ei[(NE + e) << s];
        int pos = row_ptr[dst] + rnk[e];
        unsigned int wb = f2bf(ew[e]);               // ew >= 0: sign bit 0
        csr[pos] = ((unsigned int)src << 15) | (wb >> 1);
    }
}

// --- 5. dis[n] = rsqrt(1 + sum_row ew) -- coalesced, atomic-free ---
__global__ __launch_bounds__(256) void disr_kernel(const int* __restrict__ row_ptr,
        const unsigned int* __restrict__ csr, float* __restrict__ dis) {
    int n = blockIdx.x * 4 + (threadIdx.x >> 6);
    int l = threadIdx.x & 63;
    int beg = row_ptr[n], end = row_ptr[n + 1];
    float s = 0.f;
    for (int e = beg + l; e < end; e += 64)
        s += bf2f((csr[e] & 0x7fffu) << 1);
    for (int off = 32; off; off >>= 1) s += __shfl_down(s, off);
    if (l == 0) dis[n] = rsqrtf(1.0f + s);
}

// --- 6. pull, feature-sliced, WAVE-UNIFORM: one wave = one node x one 16-feat slice.
//        slice (3.2 MB) pinned to XCD via blockIdx&7; lanes = 8 edges x 8 u32-feats;
//        row trip count uniform per wave; shfl_xor(8/16/32) reduces edge groups. ---
__global__ __launch_bounds__(256) void pull_kernel(const unsigned int* __restrict__ hb,
        const float* __restrict__ dis, const int* __restrict__ row_ptr,
        const unsigned int* __restrict__ csr, const float2* __restrict__ bias2,
        float* __restrict__ out) {
    int slice = blockIdx.x & 7;                   // measured round-robin blockIdx -> XCD
    int n = (blockIdx.x >> 3) * 4 + (threadIdx.x >> 6);
    int l = threadIdx.x & 63;
    int eo = l >> 3, fl = l & 7;                  // edge-offset 0..7, u32-feature 0..7
    const unsigned int* hs = hb + (size_t)slice * NN * 8;
    float dn = dis[n];
    unsigned int aself = hs[(size_t)n * 8 + fl];  // same addr across eo-groups: broadcast
    int beg = row_ptr[n], end = row_ptr[n + 1];
    float a0 = 0.f, a1 = 0.f;
    int e = beg;
    for (; e + 16 <= end; e += 16) {              // 16 edges/iter, unpredicated
        unsigned int cA = __builtin_nontemporal_load(csr + e + eo);
        unsigned int cB = __builtin_nontemporal_load(csr + e + 8 + eo);
        int sA = cA >> 15, sB = cB >> 15;
        float mA = dis[sA] * bits2f(cA << 17);    // dn factored out of the loop
        float mB = dis[sB] * bits2f(cB << 17);
        unsigned int uA = hs[(size_t)sA * 8 + fl];
        unsigned int uB = hs[(size_t)sB * 8 + fl];
        a0 += bits2f(uA << 16) * mA; a1 += bits2f(uA & 0xffff0000u) * mA;
        a0 += bits2f(uB << 16) * mB; a1 += bits2f(uB & 0xffff0000u) * mB;
    }
    for (; e < end; e += 8) {                     // predicated tail: c=0 -> w=0
        int ee = e + eo;
        unsigned int c = (ee < end) ? __builtin_nontemporal_load(csr + ee) : 0u;
        int s = c >> 15;
        float m = dis[s] * bits2f(c << 17);
        unsigned int u = hs[(size_t)s * 8 + fl];
        a0 += bits2f(u << 16) * m; a1 += bits2f(u & 0xffff0000u) * m;
    }
#pragma unroll
    for (int off = 8; off < 64; off <<= 1) {      // sum the 8 edge-groups
        a0 += __shfl_xor(a0, off);
        a1 += __shfl_xor(a1, off);
    }
    if (eo == 0) {
        float ss = dn * dn;
        float2 bv = bias2[slice * 8 + fl];
        f32x2 r;
        r.x = a0 * dn + bits2f(aself << 16) * ss + bv.x;
        r.y = a1 * dn + bits2f(aself & 0xffff0000u) * ss + bv.y;
        __builtin_nontemporal_store(r, (f32x2*)out + ((size_t)n * 64 + slice * 8 + fl));
    }
}

extern "C" void kernel_launch(void* const* d_in, const int* in_sizes, int n_in,
                              void* d_out, int out_size, void* d_ws, size_t ws_size,
                              hipStream_t stream) {
    const float* x  = (const float*)d_in[0];
    const int*   ei = (const int*)d_in[1];
    const float* ew = (const float*)d_in[2];
    const float* W  = (const float*)d_in[3];
    const float* b  = (const float*)d_in[4];
    float* out = (float*)d_out;

    // workspace (~43 MB)
    float*          dis     = (float*)d_ws;                    // NN
    int*            cnt     = (int*)(dis + NN);                // NN
    int*            row_ptr = cnt + NN;                        // NN+1
    int*            part    = row_ptr + NN + 1;                // 512
    int*            flag    = part + 512;                      // 1
    unsigned char*  rnk     = (unsigned char*)(((uintptr_t)(flag + 1) + 15) & ~(uintptr_t)15); // NE u8
    unsigned int*   csr     = (unsigned int*)(rnk + NE);       // NE u32
    unsigned short* hb      = (unsigned short*)(csr + NE);     // NN*128 bf16, slice-major (25.6 MB)

    detect_kernel<<<1, 64, 0, stream>>>(ei, flag);
    hipMemsetAsync(cnt, 0, NN * sizeof(int), stream);
    mgemm_kernel<<<(NN + 127) / 128, 256, 0, stream>>>(x, W, hb);
    hist_kernel<<<(NE + 255) / 256, 256, 0, stream>>>(ei, cnt, rnk, flag);
    scan1_kernel<<<NB, 256, 0, stream>>>(cnt, part);
    scan2_kernel<<<1, 512, 0, stream>>>(part);
    scan3_kernel<<<NB, 256, 0, stream>>>(cnt, part, row_ptr);
    fill_kernel<<<(NE + 255) / 256, 256, 0, stream>>>(ei, ew, rnk, row_ptr, csr, flag);
    disr_kernel<<<NN / 4, 256, 0, stream>>>(row_ptr, csr, dis);
    pull_kernel<<<8 * (NN / 4), 256, 0, stream>>>((const unsigned int*)hb, dis, row_ptr, csr,
                                                  (const float2*)b, (float*)out);
}

// Round 4
// 537.839 us; speedup vs baseline: 1.6457x; 1.4266x over previous
//
#include <hip/hip_runtime.h>

#define NN 100000
#define NE 3200000
#define D  128
#define NB ((NN + 255) / 256)   // 391 scan blocks

typedef __attribute__((ext_vector_type(8))) short bf16x8;
typedef __attribute__((ext_vector_type(4))) float f32x4;
typedef __attribute__((ext_vector_type(2))) float f32x2;

__device__ __forceinline__ float bf2f(unsigned int u) {      // u = bf16 bits
    union { unsigned int i; float f; } v; v.i = u << 16; return v.f;
}
__device__ __forceinline__ float bits2f(unsigned int u) {    // raw f32 bits
    union { unsigned int i; float f; } v; v.i = u; return v.f;
}
__device__ __forceinline__ unsigned int f2bf(float f) {      // RNE bf16
    union { float f; unsigned int i; } v; v.f = f;
    unsigned int u = v.i;
    return (u + 0x7fffu + ((u >> 16) & 1u)) >> 16;
}

// --- 0. zero cnt + detect edge_index width (int64 -> odd int32 slots all zero) ---
__global__ __launch_bounds__(256) void zero_detect_kernel(const int* __restrict__ ei,
        int* __restrict__ flag, int* __restrict__ cnt) {
    int i = blockIdx.x * 256 + threadIdx.x;
    if (i < NN) cnt[i] = 0;
    if (blockIdx.x == 0 && threadIdx.x < 64) {
        int v = ei[2 * threadIdx.x + 1];
        unsigned long long ball = __ballot(v != 0);
        if (threadIdx.x == 0) flag[0] = (ball == 0ull) ? 1 : 0;   // 1 => int64
    }
}

// --- 1. h = bf16(x @ W): MFMA 16x16x32_bf16, 128 rows/block, 4 waves. ROW-MAJOR hb. ---
__global__ __launch_bounds__(256) void mgemm_kernel(const float* __restrict__ x,
        const float* __restrict__ W, unsigned short* __restrict__ hb) {
    __shared__ unsigned short WT[16 * 128 * 8];    // 32 KB
    int t = threadIdx.x;
    {
        int n = t & 127, half = t >> 7;
        for (int it = 0; it < 8; ++it) {
            int kb = half * 8 + it;                // k-chunk 0..15
            union { unsigned short s[8]; uint4 v; } pk;
#pragma unroll
            for (int j = 0; j < 8; ++j)
                pk.s[j] = (unsigned short)f2bf(W[(kb * 8 + j) * D + n]);
            *(uint4*)&WT[(kb * 128 + n) * 8] = pk.v;
        }
    }
    __syncthreads();
    int l = t & 63, w = t >> 6;
    int q = l >> 4, m = l & 15;
    long mbase = (long)blockIdx.x * 128 + w * 32;
    long r0 = mbase + m;      if (r0 > NN - 1) r0 = NN - 1;   // clamp: no OOB reads
    long r1 = mbase + 16 + m; if (r1 > NN - 1) r1 = NN - 1;
    const float* a0p = x + r0 * D + q * 8;
    const float* a1p = x + r1 * D + q * 8;
    f32x4 acc[2][8];
#pragma unroll
    for (int mt = 0; mt < 2; ++mt)
#pragma unroll
        for (int nt = 0; nt < 8; ++nt) acc[mt][nt] = (f32x4){0.f, 0.f, 0.f, 0.f};
#pragma unroll
    for (int kc = 0; kc < 4; ++kc) {
        float4 va0 = *(const float4*)(a0p + kc * 32);
        float4 va1 = *(const float4*)(a0p + kc * 32 + 4);
        float4 vb0 = *(const float4*)(a1p + kc * 32);
        float4 vb1 = *(const float4*)(a1p + kc * 32 + 4);
        union { unsigned short s[8]; bf16x8 v; } ua, ub;
        ua.s[0] = (unsigned short)f2bf(va0.x); ua.s[1] = (unsigned short)f2bf(va0.y);
        ua.s[2] = (unsigned short)f2bf(va0.z); ua.s[3] = (unsigned short)f2bf(va0.w);
        ua.s[4] = (unsigned short)f2bf(va1.x); ua.s[5] = (unsigned short)f2bf(va1.y);
        ua.s[6] = (unsigned short)f2bf(va1.z); ua.s[7] = (unsigned short)f2bf(va1.w);
        ub.s[0] = (unsigned short)f2bf(vb0.x); ub.s[1] = (unsigned short)f2bf(vb0.y);
        ub.s[2] = (unsigned short)f2bf(vb0.z); ub.s[3] = (unsigned short)f2bf(vb0.w);
        ub.s[4] = (unsigned short)f2bf(vb1.x); ub.s[5] = (unsigned short)f2bf(vb1.y);
        ub.s[6] = (unsigned short)f2bf(vb1.z); ub.s[7] = (unsigned short)f2bf(vb1.w);
        const bf16x8* bp = (const bf16x8*)WT + (kc * 4 + q) * 128 + m;
#pragma unroll
        for (int nt = 0; nt < 8; ++nt) {
            bf16x8 bfr = bp[nt * 16];
            acc[0][nt] = __builtin_amdgcn_mfma_f32_16x16x32_bf16(ua.v, bfr, acc[0][nt], 0, 0, 0);
            acc[1][nt] = __builtin_amdgcn_mfma_f32_16x16x32_bf16(ub.v, bfr, acc[1][nt], 0, 0, 0);
        }
    }
#pragma unroll
    for (int mt = 0; mt < 2; ++mt) {
        long rowbase = mbase + mt * 16;
#pragma unroll
        for (int nt = 0; nt < 8; ++nt)
#pragma unroll
            for (int r = 0; r < 4; ++r) {
                long row = rowbase + q * 4 + r;      // C/D: col=lane&15, row=quad*4+reg
                if (row < NN)
                    hb[row * D + nt * 16 + m] = (unsigned short)f2bf(acc[mt][nt][r]);
            }
    }
}

// --- 2. count per dst; atomic RETURN VALUE = within-bucket rank (u8: max in-deg ~70) ---
__global__ void hist_kernel(const int* __restrict__ ei, int* __restrict__ cnt,
                            unsigned char* __restrict__ rnk, const int* __restrict__ flag) {
    int s = flag[0];
    int e = blockIdx.x * 256 + threadIdx.x;
    if (e < NE) {
        int d = s ? (int)((const long*)ei)[NE + e] : ei[NE + e];   // coalesced 8B when i64
        int r = atomicAdd(&cnt[d], 1);
        rnk[e] = (unsigned char)r;
    }
}

// --- 3a/3b/3c. three-phase exclusive scan -> row_ptr ---
__global__ __launch_bounds__(256) void scan1_kernel(const int* __restrict__ cnt,
                                                    int* __restrict__ part) {
    __shared__ int red[256];
    int t = threadIdx.x, i = blockIdx.x * 256 + t;
    red[t] = (i < NN) ? cnt[i] : 0;
    __syncthreads();
    for (int off = 128; off; off >>= 1) {
        if (t < off) red[t] += red[t + off];
        __syncthreads();
    }
    if (t == 0) part[blockIdx.x] = red[0];
}
__global__ __launch_bounds__(512) void scan2_kernel(int* __restrict__ part) {
    __shared__ int s[512];
    int t = threadIdx.x;
    s[t] = (t < NB) ? part[t] : 0;
    __syncthreads();
    for (int off = 1; off < 512; off <<= 1) {
        int v = (t >= off) ? s[t - off] : 0;
        __syncthreads();
        s[t] += v;
        __syncthreads();
    }
    if (t < NB) part[t] = (t > 0) ? s[t - 1] : 0;
}
__global__ __launch_bounds__(256) void scan3_kernel(const int* __restrict__ cnt,
        const int* __restrict__ part, int* __restrict__ row_ptr) {
    __shared__ int s[256];
    int t = threadIdx.x, i = blockIdx.x * 256 + t;
    int v = (i < NN) ? cnt[i] : 0;
    s[t] = v;
    __syncthreads();
    for (int off = 1; off < 256; off <<= 1) {
        int u = (t >= off) ? s[t - off] : 0;
        __syncthreads();
        s[t] += u;
        __syncthreads();
    }
    int base = part[blockIdx.x];
    if (i < NN) row_ptr[i] = base + s[t] - v;
    if (i == NN - 1) row_ptr[NN] = base + s[t];
}

// --- 4. bucket fill, atomic-free: pos = row_ptr[dst] + rnk[e] ---
__global__ void fill_kernel(const int* __restrict__ ei, const float* __restrict__ ew,
                            const unsigned char* __restrict__ rnk,
                            const int* __restrict__ row_ptr, unsigned int* __restrict__ csr,
                            const int* __restrict__ flag) {
    int s = flag[0];
    int e = blockIdx.x * 256 + threadIdx.x;
    if (e < NE) {
        int src, dst;
        if (s) { src = (int)((const long*)ei)[e]; dst = (int)((const long*)ei)[NE + e]; }
        else   { src = ei[e];                     dst = ei[NE + e]; }
        int pos = row_ptr[dst] + rnk[e];
        unsigned int wb = f2bf(ew[e]);               // ew >= 0: sign bit 0
        csr[pos] = ((unsigned int)src << 15) | (wb >> 1);
    }
}

// --- 5. dis[n] = rsqrt(1 + sum_row ew) -- coalesced, atomic-free ---
__global__ __launch_bounds__(256) void disr_kernel(const int* __restrict__ row_ptr,
        const unsigned int* __restrict__ csr, float* __restrict__ dis) {
    int n = blockIdx.x * 4 + (threadIdx.x >> 6);
    int l = threadIdx.x & 63;
    int beg = row_ptr[n], end = row_ptr[n + 1];
    float s = 0.f;
    for (int e = beg + l; e < end; e += 64)
        s += bf2f((csr[e] & 0x7fffu) << 1);
    for (int off = 32; off; off >>= 1) s += __shfl_down(s, off);
    if (l == 0) dis[n] = rsqrtf(1.0f + s);
}

// --- 6. pull: out = Agg(h) + bias ; one wave/node, 16 gathers in flight, dn factored out ---
__global__ __launch_bounds__(256) void pull_kernel(const unsigned int* __restrict__ hb,
        const float* __restrict__ dis, const int* __restrict__ row_ptr,
        const unsigned int* __restrict__ csr, const float2* __restrict__ bias2,
        float* __restrict__ out) {
    int t = blockIdx.x * 256 + threadIdx.x;
    int n = t >> 6, l = t & 63;
    float dn = dis[n];
    unsigned int a = hb[n * 64 + l];                 // self-loop term (applied at end)
    float accx = 0.f, accy = 0.f;                    // loop sums exclude dn factor
    int e = row_ptr[n], end = row_ptr[n + 1];
    for (; e + 15 < end; e += 16) {                  // 16 independent row-gathers in flight
        unsigned int c[16];
#pragma unroll
        for (int j = 0; j < 16; ++j) c[j] = __builtin_nontemporal_load(csr + e + j);
        int s_[16];
#pragma unroll
        for (int j = 0; j < 16; ++j) s_[j] = c[j] >> 15;
        unsigned int u[16];
#pragma unroll
        for (int j = 0; j < 16; ++j) u[j] = hb[s_[j] * 64 + l];
#pragma unroll
        for (int j = 0; j < 16; ++j) {
            float m = dis[s_[j]] * bits2f(c[j] << 17);   // w decode = 1 shift
            accx += bits2f(u[j] << 16) * m;
            accy += bits2f(u[j] & 0xffff0000u) * m;
        }
    }
    for (; e + 3 < end; e += 4) {
        unsigned int c[4];
#pragma unroll
        for (int j = 0; j < 4; ++j) c[j] = __builtin_nontemporal_load(csr + e + j);
        int s_[4];
#pragma unroll
        for (int j = 0; j < 4; ++j) s_[j] = c[j] >> 15;
        unsigned int u[4];
#pragma unroll
        for (int j = 0; j < 4; ++j) u[j] = hb[s_[j] * 64 + l];
#pragma unroll
        for (int j = 0; j < 4; ++j) {
            float m = dis[s_[j]] * bits2f(c[j] << 17);
            accx += bits2f(u[j] << 16) * m;
            accy += bits2f(u[j] & 0xffff0000u) * m;
        }
    }
    for (; e < end; ++e) {
        unsigned int c0 = __builtin_nontemporal_load(csr + e);
        int s0 = c0 >> 15;
        unsigned int u0 = hb[s0 * 64 + l];
        float m = dis[s0] * bits2f(c0 << 17);
        accx += bits2f(u0 << 16) * m;
        accy += bits2f(u0 & 0xffff0000u) * m;
    }
    float ss = dn * dn;
    float2 bv = bias2[l];
    f32x2 r;
    r.x = accx * dn + bits2f(a << 16) * ss + bv.x;
    r.y = accy * dn + bits2f(a & 0xffff0000u) * ss + bv.y;
    __builtin_nontemporal_store(r, (f32x2*)out + ((size_t)n * 64 + l));
}

extern "C" void kernel_launch(void* const* d_in, const int* in_sizes, int n_in,
                              void* d_out, int out_size, void* d_ws, size_t ws_size,
                              hipStream_t stream) {
    const float* x  = (const float*)d_in[0];
    const int*   ei = (const int*)d_in[1];
    const float* ew = (const float*)d_in[2];
    const float* W  = (const float*)d_in[3];
    const float* b  = (const float*)d_in[4];
    float* out = (float*)d_out;

    // workspace (~43 MB)
    float*          dis     = (float*)d_ws;                    // NN
    int*            cnt     = (int*)(dis + NN);                // NN
    int*            row_ptr = cnt + NN;                        // NN+1
    int*            part    = row_ptr + NN + 1;                // 512
    int*            flag    = part + 512;                      // 1
    unsigned char*  rnk     = (unsigned char*)(((uintptr_t)(flag + 1) + 15) & ~(uintptr_t)15); // NE u8
    unsigned int*   csr     = (unsigned int*)(rnk + NE);       // NE u32
    unsigned short* hb      = (unsigned short*)(csr + NE);     // NN*128 bf16, row-major (25.6 MB)

    zero_detect_kernel<<<NB, 256, 0, stream>>>(ei, flag, cnt);
    mgemm_kernel<<<(NN + 127) / 128, 256, 0, stream>>>(x, W, hb);
    hist_kernel<<<(NE + 255) / 256, 256, 0, stream>>>(ei, cnt, rnk, flag);
    scan1_kernel<<<NB, 256, 0, stream>>>(cnt, part);
    scan2_kernel<<<1, 512, 0, stream>>>(part);
    scan3_kernel<<<NB, 256, 0, stream>>>(cnt, part, row_ptr);
    fill_kernel<<<(NE + 255) / 256, 256, 0, stream>>>(ei, ew, rnk, row_ptr, csr, flag);
    disr_kernel<<<NN / 4, 256, 0, stream>>>(row_ptr, csr, dis);
    pull_kernel<<<(NN * 64) / 256, 256, 0, stream>>>((const unsigned int*)hb, dis, row_ptr, csr,
                                                     (const float2*)b, (float*)out);
}

// Round 6
// 382.330 us; speedup vs baseline: 2.3151x; 1.4067x over previous
//
#include <hip/hip_runtime.h>

#define NN 100000
#define NE 3200000
#define D  128
#define NBUCK 391               // coarse buckets of 256 dst nodes (dst>>8)

typedef __attribute__((ext_vector_type(8))) short bf16x8;
typedef __attribute__((ext_vector_type(4))) float f32x4;
typedef __attribute__((ext_vector_type(2))) float f32x2;

__device__ __forceinline__ float bf2f(unsigned int u) {      // u = bf16 bits
    union { unsigned int i; float f; } v; v.i = u << 16; return v.f;
}
__device__ __forceinline__ float bits2f(unsigned int u) {    // raw f32 bits
    union { unsigned int i; float f; } v; v.i = u; return v.f;
}
__device__ __forceinline__ unsigned int f2bf(float f) {      // RNE bf16
    union { float f; unsigned int i; } v; v.f = f;
    unsigned int u = v.i;
    return (u + 0x7fffu + ((u >> 16) & 1u)) >> 16;
}

// --- 0. zero gcnt + detect edge_index width (int64 -> odd int32 slots all zero) ---
__global__ __launch_bounds__(512) void zero_detect_kernel(const int* __restrict__ ei,
        int* __restrict__ flag, int* __restrict__ gcnt) {
    int t = threadIdx.x;
    if (t < NBUCK) gcnt[t] = 0;
    if (t < 64) {
        int v = ei[2 * t + 1];
        unsigned long long ball = __ballot(v != 0);
        if (t == 0) flag[0] = (ball == 0ull) ? 1 : 0;   // 1 => int64
    }
}

// --- 1. coarse count: per-block LDS hist over 391 buckets, one returned atomic per
//        (block,bucket) -> 153K global atomics instead of 3.2M ---
__global__ __launch_bounds__(256) void count1_kernel(const int* __restrict__ ei,
        int* __restrict__ gcnt, int* __restrict__ blockbase, const int* __restrict__ flag) {
    __shared__ int h[NBUCK + 1];
    int t = threadIdx.x, b = blockIdx.x;
    int s = flag[0];
    for (int j = t; j <= NBUCK; j += 256) h[j] = 0;
    __syncthreads();
    long e0 = (long)b * 8192;
    for (int it = 0; it < 32; ++it) {
        long e = e0 + it * 256 + t;
        if (e < NE) {
            int d = s ? (int)((const long*)ei)[NE + e] : ei[NE + e];
            atomicAdd(&h[d >> 8], 1);
        }
    }
    __syncthreads();
    for (int j = t; j < NBUCK; j += 256) {
        int bb = atomicAdd(&gcnt[j], h[j]);
        blockbase[b * NBUCK + j] = bb;
    }
}

// --- 2. scatter edges into bucket-contiguous tmp (u64: dlow<<32 | csr-word).
//        position = gbase[bkt] + blockbase[b][bkt] + LDS-cursor rank (atomic-free global). ---
__global__ __launch_bounds__(512) void scatter1_kernel(const int* __restrict__ ei,
        const float* __restrict__ ew, const int* __restrict__ gcnt,
        const int* __restrict__ blockbase, const int* __restrict__ flag,
        unsigned long long* __restrict__ tmp, int* __restrict__ gbase) {
    __shared__ int gb[512];          // inclusive scan of bucket counts
    __shared__ int bb[NBUCK + 1];
    __shared__ int cur[NBUCK + 1];
    int t = threadIdx.x, b = blockIdx.x;
    int s = flag[0];
    gb[t] = (t < NBUCK) ? gcnt[t] : 0;
    if (t <= NBUCK) cur[t] = 0;
    if (t < NBUCK) bb[t] = blockbase[b * NBUCK + t];
    __syncthreads();
    for (int off = 1; off < 512; off <<= 1) {        // Hillis-Steele inclusive
        int v = (t >= off) ? gb[t - off] : 0;
        __syncthreads();
        gb[t] += v;
        __syncthreads();
    }
    if (b == 0) {                                    // publish exclusive bases for build2
        if (t < NBUCK) gbase[t] = (t > 0) ? gb[t - 1] : 0;
        if (t == 0) gbase[NBUCK] = NE;
    }
    long e0 = (long)b * 8192;
    for (int it = 0; it < 16; ++it) {
        long e = e0 + it * 512 + t;
        if (e < NE) {
            int src, dst;
            if (s) { src = (int)((const long*)ei)[e]; dst = (int)((const long*)ei)[NE + e]; }
            else   { src = ei[e];                     dst = ei[NE + e]; }
            float w = ew[e];
            int bkt = dst >> 8, dlow = dst & 255;
            int r = atomicAdd(&cur[bkt], 1);
            int base = (bkt > 0) ? gb[bkt - 1] : 0;
            unsigned int word = ((unsigned int)src << 15) | (f2bf(w) >> 1);
            tmp[base + bb[bkt] + r] = ((unsigned long long)(unsigned int)dlow << 32) | word;
        }
    }
}

// --- 3. per-bucket: 256-slot LDS hist + scan -> row_ptr; scatter tmp -> final csr ---
__global__ __launch_bounds__(256) void build2_kernel(const unsigned long long* __restrict__ tmp,
        const int* __restrict__ gbase, int* __restrict__ row_ptr, unsigned int* __restrict__ csr) {
    __shared__ int hist[256], excl[256], cur[256];
    int t = threadIdx.x, k = blockIdx.x;
    int base = gbase[k], endb = gbase[k + 1];
    hist[t] = 0; cur[t] = 0;
    __syncthreads();
    for (int i = base + t; i < endb; i += 256) {
        unsigned long long v = tmp[i];
        atomicAdd(&hist[(int)(v >> 32)], 1);
    }
    __syncthreads();
    excl[t] = hist[t];
    __syncthreads();
    for (int off = 1; off < 256; off <<= 1) {        // inclusive scan
        int v = (t >= off) ? excl[t - off] : 0;
        __syncthreads();
        excl[t] += v;
        __syncthreads();
    }
    int ex = excl[t] - hist[t];                      // exclusive (own slot only)
    int node = k * 256 + t;
    if (node < NN) row_ptr[node] = base + ex;
    if (node == NN - 1) row_ptr[NN] = NE;
    __syncthreads();
    excl[t] = ex;                                    // now holds exclusive for all slots
    __syncthreads();
    for (int i = base + t; i < endb; i += 256) {
        unsigned long long v = tmp[i];
        int dl = (int)(v >> 32);
        int r = atomicAdd(&cur[dl], 1);
        csr[base + excl[dl] + r] = (unsigned int)v;
    }
}

// --- 4. dis[n] = rsqrt(1 + sum_row ew) -- coalesced, atomic-free ---
__global__ __launch_bounds__(256) void disr_kernel(const int* __restrict__ row_ptr,
        const unsigned int* __restrict__ csr, float* __restrict__ dis) {
    int n = blockIdx.x * 4 + (threadIdx.x >> 6);
    int l = threadIdx.x & 63;
    int beg = row_ptr[n], end = row_ptr[n + 1];
    float s = 0.f;
    for (int e = beg + l; e < end; e += 64)
        s += bf2f((csr[e] & 0x7fffu) << 1);
    for (int off = 32; off; off >>= 1) s += __shfl_down(s, off);
    if (l == 0) dis[n] = rsqrtf(1.0f + s);
}

// --- 5. h' = bf16(dis[row] * (x @ W)): prescaled rows kill the per-edge dis[src] gather ---
__global__ __launch_bounds__(256) void mgemm_kernel(const float* __restrict__ x,
        const float* __restrict__ W, const float* __restrict__ dis,
        unsigned short* __restrict__ hb) {
    __shared__ unsigned short WT[16 * 128 * 8];    // 32 KB
    int t = threadIdx.x;
    {
        int n = t & 127, half = t >> 7;
        for (int it = 0; it < 8; ++it) {
            int kb = half * 8 + it;                // k-chunk 0..15
            union { unsigned short s[8]; uint4 v; } pk;
#pragma unroll
            for (int j = 0; j < 8; ++j)
                pk.s[j] = (unsigned short)f2bf(W[(kb * 8 + j) * D + n]);
            *(uint4*)&WT[(kb * 128 + n) * 8] = pk.v;
        }
    }
    __syncthreads();
    int l = t & 63, w = t >> 6;
    int q = l >> 4, m = l & 15;
    long mbase = (long)blockIdx.x * 128 + w * 32;
    long r0 = mbase + m;      if (r0 > NN - 1) r0 = NN - 1;   // clamp: no OOB reads
    long r1 = mbase + 16 + m; if (r1 > NN - 1) r1 = NN - 1;
    const float* a0p = x + r0 * D + q * 8;
    const float* a1p = x + r1 * D + q * 8;
    f32x4 acc[2][8];
#pragma unroll
    for (int mt = 0; mt < 2; ++mt)
#pragma unroll
        for (int nt = 0; nt < 8; ++nt) acc[mt][nt] = (f32x4){0.f, 0.f, 0.f, 0.f};
#pragma unroll
    for (int kc = 0; kc < 4; ++kc) {
        float4 va0 = *(const float4*)(a0p + kc * 32);
        float4 va1 = *(const float4*)(a0p + kc * 32 + 4);
        float4 vb0 = *(const float4*)(a1p + kc * 32);
        float4 vb1 = *(const float4*)(a1p + kc * 32 + 4);
        union { unsigned short s[8]; bf16x8 v; } ua, ub;
        ua.s[0] = (unsigned short)f2bf(va0.x); ua.s[1] = (unsigned short)f2bf(va0.y);
        ua.s[2] = (unsigned short)f2bf(va0.z); ua.s[3] = (unsigned short)f2bf(va0.w);
        ua.s[4] = (unsigned short)f2bf(va1.x); ua.s[5] = (unsigned short)f2bf(va1.y);
        ua.s[6] = (unsigned short)f2bf(va1.z); ua.s[7] = (unsigned short)f2bf(va1.w);
        ub.s[0] = (unsigned short)f2bf(vb0.x); ub.s[1] = (unsigned short)f2bf(vb0.y);
        ub.s[2] = (unsigned short)f2bf(vb0.z); ub.s[3] = (unsigned short)f2bf(vb0.w);
        ub.s[4] = (unsigned short)f2bf(vb1.x); ub.s[5] = (unsigned short)f2bf(vb1.y);
        ub.s[6] = (unsigned short)f2bf(vb1.z); ub.s[7] = (unsigned short)f2bf(vb1.w);
        const bf16x8* bp = (const bf16x8*)WT + (kc * 4 + q) * 128 + m;
#pragma unroll
        for (int nt = 0; nt < 8; ++nt) {
            bf16x8 bfr = bp[nt * 16];
            acc[0][nt] = __builtin_amdgcn_mfma_f32_16x16x32_bf16(ua.v, bfr, acc[0][nt], 0, 0, 0);
            acc[1][nt] = __builtin_amdgcn_mfma_f32_16x16x32_bf16(ub.v, bfr, acc[1][nt], 0, 0, 0);
        }
    }
#pragma unroll
    for (int mt = 0; mt < 2; ++mt) {
        long rowbase = mbase + mt * 16;
#pragma unroll
        for (int r = 0; r < 4; ++r) {
            long row = rowbase + q * 4 + r;          // C/D: col=lane&15, row=quad*4+reg
            float dsc = dis[(row < NN) ? row : (NN - 1)];
#pragma unroll
            for (int nt = 0; nt < 8; ++nt)
                if (row < NN)
                    hb[row * D + nt * 16 + m] = (unsigned short)f2bf(acc[mt][nt][r] * dsc);
        }
    }
}

// --- 6. pull: out = dn*(sum w*h'[src] + h'[n]) + bias ; one wave/node, 8 gathers in flight ---
__global__ __launch_bounds__(256) void pull_kernel(const unsigned int* __restrict__ hb,
        const float* __restrict__ dis, const int* __restrict__ row_ptr,
        const unsigned int* __restrict__ csr, const float2* __restrict__ bias2,
        float* __restrict__ out) {
    int t = blockIdx.x * 256 + threadIdx.x;
    int n = t >> 6, l = t & 63;
    float dn = dis[n];
    unsigned int a = hb[n * 64 + l];                 // self term h'[n]
    float accx = bits2f(a << 16);
    float accy = bits2f(a & 0xffff0000u);
    int e = row_ptr[n], end = row_ptr[n + 1];
    for (; e + 7 < end; e += 8) {                    // 8 independent row-gathers in flight
        unsigned int c[8];
#pragma unroll
        for (int j = 0; j < 8; ++j) c[j] = __builtin_nontemporal_load(csr + e + j);
        int s_[8];
#pragma unroll
        for (int j = 0; j < 8; ++j) s_[j] = c[j] >> 15;
        unsigned int u[8];
#pragma unroll
        for (int j = 0; j < 8; ++j) u[j] = hb[s_[j] * 64 + l];
#pragma unroll
        for (int j = 0; j < 8; ++j) {
            float m = bits2f(c[j] << 17);            // w decode = 1 shift
            accx += bits2f(u[j] << 16) * m;
            accy += bits2f(u[j] & 0xffff0000u) * m;
        }
    }
    for (; e + 1 < end; e += 2) {
        unsigned int c0 = __builtin_nontemporal_load(csr + e);
        unsigned int c1 = __builtin_nontemporal_load(csr + e + 1);
        int s0 = c0 >> 15, s1 = c1 >> 15;
        unsigned int u0 = hb[s0 * 64 + l];
        unsigned int u1 = hb[s1 * 64 + l];
        float m0 = bits2f(c0 << 17), m1 = bits2f(c1 << 17);
        accx += bits2f(u0 << 16) * m0; accy += bits2f(u0 & 0xffff0000u) * m0;
        accx += bits2f(u1 << 16) * m1; accy += bits2f(u1 & 0xffff0000u) * m1;
    }
    if (e < end) {
        unsigned int c0 = __builtin_nontemporal_load(csr + e);
        int s0 = c0 >> 15;
        unsigned int u0 = hb[s0 * 64 + l];
        float m0 = bits2f(c0 << 17);
        accx += bits2f(u0 << 16) * m0; accy += bits2f(u0 & 0xffff0000u) * m0;
    }
    float2 bv = bias2[l];
    f32x2 r;
    r.x = accx * dn + bv.x;
    r.y = accy * dn + bv.y;
    __builtin_nontemporal_store(r, (f32x2*)out + ((size_t)n * 64 + l));
}

extern "C" void kernel_launch(void* const* d_in, const int* in_sizes, int n_in,
                              void* d_out, int out_size, void* d_ws, size_t ws_size,
                              hipStream_t stream) {
    const float* x  = (const float*)d_in[0];
    const int*   ei = (const int*)d_in[1];
    const float* ew = (const float*)d_in[2];
    const float* W  = (const float*)d_in[3];
    const float* b  = (const float*)d_in[4];
    float* out = (float*)d_out;

    // workspace (~40 MB). tmp (bucketed edges) and hb (GEMM output) are
    // non-overlapping in TIME (bucketing finishes before mgemm writes hb) -> aliased.
    unsigned long long* tmp = (unsigned long long*)d_ws;           // NE u64 (25.6 MB)
    unsigned short*     hb  = (unsigned short*)d_ws;               // NN*128 bf16 (25.6 MB)
    unsigned int*       csr = (unsigned int*)((char*)d_ws + (size_t)NE * 8);  // NE u32
    float*              dis = (float*)(csr + NE);                  // NN
    int*            row_ptr = (int*)(dis + NN);                    // NN+1
    int*            gcnt    = row_ptr + NN + 1;                    // NBUCK
    int*            gbase   = gcnt + NBUCK;                        // NBUCK+1
    int*            flag    = gbase + NBUCK + 1;                   // 1
    int*          blockbase = flag + 1;                            // NBUCK*NBUCK (612 KB)

    zero_detect_kernel<<<1, 512, 0, stream>>>(ei, flag, gcnt);
    count1_kernel<<<NBUCK, 256, 0, stream>>>(ei, gcnt, blockbase, flag);
    scatter1_kernel<<<NBUCK, 512, 0, stream>>>(ei, ew, gcnt, blockbase, flag, tmp, gbase);
    build2_kernel<<<NBUCK, 256, 0, stream>>>(tmp, gbase, row_ptr, csr);
    disr_kernel<<<NN / 4, 256, 0, stream>>>(row_ptr, csr, dis);
    mgemm_kernel<<<(NN + 127) / 128, 256, 0, stream>>>(x, W, dis, hb);
    pull_kernel<<<(NN * 64) / 256, 256, 0, stream>>>((const unsigned int*)hb, dis, row_ptr, csr,
                                                     (const float2*)b, (float*)out);
}